// Round 1
// 409.369 us; speedup vs baseline: 1.0023x; 1.0023x over previous
//
#include <hip/hip_runtime.h>
#include <hip/hip_bf16.h>
#include <stdint.h>

#define D 64
typedef __hip_bfloat16 bf16;
typedef unsigned short u16;

__device__ __forceinline__ float bf2f(u16 u) { return __uint_as_float(((uint32_t)u) << 16); }

template <bool F32>
__device__ __forceinline__ float ld(const void* p, int i) {
    if constexpr (F32) return ((const float*)p)[i];
    else return bf2f(((const u16*)p)[i]);
}

// ---- dtype oracle (proven): flags[0]=1 -> fp32 floats; flags[1]=1 -> int32 idx ----
__global__ __launch_bounds__(256) void detect_kernel(const void* x, const int* ei, int* flags) {
    __shared__ float smax[256];
    __shared__ int sor[256];
    int t = threadIdx.x;
    const u16* xs = (const u16*)x;
    float mx = 0.f;
#pragma unroll
    for (int i = 0; i < 16; ++i) {
        float a = fabsf(bf2f(xs[t * 16 + i]));
        if (!(a == a)) a = 1e30f;
        mx = fmaxf(mx, a);
    }
    int any = 0;
#pragma unroll
    for (int i = 0; i < 8; ++i) any |= ei[2 * (t * 8 + i) + 1];
    smax[t] = mx; sor[t] = any;
    __syncthreads();
    for (int s = 128; s > 0; s >>= 1) {
        if (t < s) { smax[t] = fmaxf(smax[t], smax[t + s]); sor[t] |= sor[t + s]; }
        __syncthreads();
    }
    if (t == 0) { flags[0] = (smax[0] > 1000.f) ? 1 : 0; flags[1] = (sor[0] != 0) ? 1 : 0; }
}

// ---- prep_all: nt (h0 -> bf16 table) + combined weights + direct bucket fill ----
//  Combined-weight layout is now k-PAIR interleaved for float2 loads in the layer:
//  float index = l*12288 + (k>>1)*384 + 2*r + (k&1)   (r = gate*64 + c)
#define N_WCT 36864
#define N_WTH 12288
#define N_B   384
template <bool F32>
__device__ __forceinline__ void nt_body(const void* x, const void* Wnt, const void* bnt,
                                        u16* ht, int N, int blk) {
    int gid = blk * 256 + threadIdx.x;
    if (gid >= N * D) return;
    int n = gid >> 6, c = gid & 63;
    float acc = ld<F32>(bnt, c);
#pragma unroll
    for (int k = 0; k < 6; ++k)
        acc = fmaf(ld<F32>(x, n * 6 + k), ld<F32>(Wnt, c * 6 + k), acc);
    ht[gid] = __bfloat16_as_ushort(__float2bfloat16(fmaxf(acc, 0.f)));
}
template <bool F32>
__device__ __forceinline__ void wc_body(const void* W, const void* Wih, const void* Whh,
                                        const void* bih, const void* bhh,
                                        float* WCT, float* WTh, float* B, int blk) {
    int i = blk * 256 + threadIdx.x;
    if (i < N_WCT) {
        int l = i / 12288, rem = i % 12288, k = rem / 192, r = rem % 192;
        float acc = 0.f;
#pragma unroll 8
        for (int j = 0; j < 64; ++j)
            acc = fmaf(ld<F32>(W, l * 4096 + k * 64 + j), ld<F32>(Wih, r * 64 + j), acc);
        WCT[l * 12288 + (k >> 1) * 384 + 2 * r + (k & 1)] = acc;
    } else if (i < N_WCT + N_WTH) {
        int rem = i - N_WCT;
        int k = rem / 192, r = rem % 192;
        WTh[(k >> 1) * 384 + 2 * r + (k & 1)] = ld<F32>(Whh, r * 64 + k);
    } else if (i < N_WCT + N_WTH + N_B) {
        int rem = i - N_WCT - N_WTH;
        B[rem] = (rem < 192) ? ld<F32>(bih, rem) : ld<F32>(bhh, rem - 192);
    }
}
__global__ __launch_bounds__(256) void prep_all(const int* __restrict__ flags,
                                                const void* x, const void* Wnt, const void* bnt,
                                                const void* W, const void* Wih, const void* Whh,
                                                const void* bih, const void* bhh,
                                                u16* ht, float* WCT, float* WTh, float* B,
                                                const int* __restrict__ ei, int* __restrict__ cnt,
                                                u16* __restrict__ ss16, int* __restrict__ novf,
                                                int* __restrict__ ovf,
                                                int E, int N, int NT_BLK, int WC_BLK) {
    int b = blockIdx.x;
    if (b < NT_BLK) {
        if (flags[0]) nt_body<true>(x, Wnt, bnt, ht, N, b);
        else          nt_body<false>(x, Wnt, bnt, ht, N, b);
    } else if (b < NT_BLK + WC_BLK) {
        if (flags[0]) wc_body<true>(W, Wih, Whh, bih, bhh, WCT, WTh, B, b - NT_BLK);
        else          wc_body<false>(W, Wih, Whh, bih, bhh, WCT, WTh, B, b - NT_BLK);
    } else {
        // fill_direct: one atomic counts AND allocates the bucket slot
        int i = (b - NT_BLK - WC_BLK) * 256 + threadIdx.x;
        if (i >= E) return;
        int src, dst;
        if (flags[1]) { src = ei[i];     dst = ei[E + i]; }
        else          { src = ei[2 * i]; dst = ei[2 * (E + i)]; }
        if ((unsigned)src >= (unsigned)N || (unsigned)dst >= (unsigned)N) return;
        int pos = atomicAdd(&cnt[dst], 1);
        if (pos < 64) ss16[(size_t)dst * 64 + pos] = (u16)src;
        else { int o = atomicAdd(novf, 1); ovf[2 * o] = dst; ovf[2 * o + 1] = src; }
    }
}

// ======= fused layer: 32 nodes/block, 8 nodes/wave; lane = channel =======
// Gather: per-node index vector preloaded lane-parallel (1 coalesced 128B load),
//         indices broadcast via __shfl -> row gathers (16-deep MLP).
// Gates:  k-pair float2 weight loads (half the instrs), float4 LDS reads,
//         8-node register accumulators amortize each weight load 2x vs before.
#define NPB 32
#define LSTR 68
__global__ __launch_bounds__(256) void layer_fused(const int* __restrict__ flags,
                                                   const u16* __restrict__ ht,
                                                   const int* __restrict__ cnt,
                                                   const u16* __restrict__ ss16,
                                                   const int* __restrict__ novf,
                                                   const int* __restrict__ ovf,
                                                   const float* __restrict__ WC,   // [32 kpair][192] float2
                                                   const float* __restrict__ WTh,  // [32 kpair][192] float2
                                                   const float* __restrict__ B,    // 384 fp32
                                                   u16* __restrict__ houtb,        // mid layers (bf16)
                                                   void* __restrict__ dout,        // last layer
                                                   int N) {
    __shared__ float LA[NPB * LSTR];
    __shared__ float LH[NPB * LSTR];
    int t = threadIdx.x;
    int n0 = blockIdx.x * NPB;
    int lane = t & 63;
    int w8 = (t >> 6) * 8;

    {   // stage own h rows: 16B coalesced bf16x8 loads, unpack to fp32 LDS (float4 stores)
        int row = t >> 3, col = (t & 7) * 8;
        bool v = (n0 + row) < N;
        uint4 vh = make_uint4(0u, 0u, 0u, 0u);
        if (v) vh = *(const uint4*)(ht + (size_t)(n0 + row) * D + col);
        float4 f0, f1;
        f0.x = bf2f((u16)(vh.x & 0xffff)); f0.y = bf2f((u16)(vh.x >> 16));
        f0.z = bf2f((u16)(vh.y & 0xffff)); f0.w = bf2f((u16)(vh.y >> 16));
        f1.x = bf2f((u16)(vh.z & 0xffff)); f1.y = bf2f((u16)(vh.z >> 16));
        f1.z = bf2f((u16)(vh.w & 0xffff)); f1.w = bf2f((u16)(vh.w >> 16));
        *(float4*)&LH[row * LSTR + col]     = f0;
        *(float4*)&LH[row * LSTR + col + 4] = f1;
    }

    // ---- gather: preload counts + index vectors for all 8 nodes (independent loads) ----
    int dg[8]; int iv[8];
#pragma unroll
    for (int p = 0; p < 8; ++p) {
        int n = n0 + w8 + p;
        dg[p] = 0; iv[p] = 0;
        if (n < N) {
            int c = cnt[n]; dg[p] = (c > 64) ? 64 : c;
            iv[p] = (int)ss16[(size_t)n * 64 + lane];  // lane j holds bucket[j]
        }
    }
#pragma unroll
    for (int p = 0; p < 8; ++p) {
        float acc = 0.f;
        int dgp = dg[p], ivp = iv[p];
        int j = 0;
        for (; j + 15 < dgp; j += 16) {
            int ix[16]; float a[16];
#pragma unroll
            for (int q = 0; q < 16; ++q) ix[q] = __shfl(ivp, j + q);
#pragma unroll
            for (int q = 0; q < 16; ++q) a[q] = bf2f(ht[(size_t)ix[q] * D + lane]);
            acc += (((a[0] + a[1]) + (a[2] + a[3])) + ((a[4] + a[5]) + (a[6] + a[7])))
                 + (((a[8] + a[9]) + (a[10] + a[11])) + ((a[12] + a[13]) + (a[14] + a[15])));
        }
        for (; j + 7 < dgp; j += 8) {
            int ix[8]; float a[8];
#pragma unroll
            for (int q = 0; q < 8; ++q) ix[q] = __shfl(ivp, j + q);
#pragma unroll
            for (int q = 0; q < 8; ++q) a[q] = bf2f(ht[(size_t)ix[q] * D + lane]);
            acc += ((a[0] + a[1]) + (a[2] + a[3])) + ((a[4] + a[5]) + (a[6] + a[7]));
        }
        for (; j + 3 < dgp; j += 4) {
            int ix[4]; float a[4];
#pragma unroll
            for (int q = 0; q < 4; ++q) ix[q] = __shfl(ivp, j + q);
#pragma unroll
            for (int q = 0; q < 4; ++q) a[q] = bf2f(ht[(size_t)ix[q] * D + lane]);
            acc += (a[0] + a[1]) + (a[2] + a[3]);
        }
        for (; j < dgp; ++j) acc += bf2f(ht[(size_t)__shfl(ivp, j) * D + lane]);
        LA[(w8 + p) * LSTR + lane] = acc;
    }
    __syncthreads();
    {   // exact overflow drain (novf==0 in practice: one scalar load + barrier)
        int nv = novf[0];
        if (nv > 0) {
            for (int o = (t >> 6); o < nv; o += 4) {
                int dst = ovf[2 * o];
                if (dst >= n0 && dst < n0 + NPB) {
                    int src = ovf[2 * o + 1];
                    atomicAdd(&LA[(dst - n0) * LSTR + lane], bf2f(ht[(size_t)src * D + lane]));
                }
            }
        }
    }
    __syncthreads();

    // ---- gates: lane = channel; 8-node accumulators; float2 k-pair weights ----
    const float2* W2 = (const float2*)WC;
    const float2* V2 = (const float2*)WTh;
    float ra[8], za[8], ia[8], ha[8];
    {
        float br = B[lane] + B[192 + lane];
        float bz = B[64 + lane] + B[256 + lane];
        float bi = B[128 + lane];
        float bh = B[320 + lane];
#pragma unroll
        for (int p = 0; p < 8; ++p) { ra[p] = br; za[p] = bz; ia[p] = bi; ha[p] = bh; }
    }
#pragma unroll 1
    for (int kq = 0; kq < 16; ++kq) {
        int b0 = (2 * kq) * 192 + lane;
        float2 wr0 = W2[b0];       float2 wr1 = W2[b0 + 192];
        float2 wz0 = W2[b0 + 64];  float2 wz1 = W2[b0 + 256];
        float2 wi0 = W2[b0 + 128]; float2 wi1 = W2[b0 + 320];
        float2 vr0 = V2[b0];       float2 vr1 = V2[b0 + 192];
        float2 vz0 = V2[b0 + 64];  float2 vz1 = V2[b0 + 256];
        float2 vn0 = V2[b0 + 128]; float2 vn1 = V2[b0 + 320];
#pragma unroll
        for (int p = 0; p < 8; ++p) {
            int rr = w8 + p;
            float4 a  = *(const float4*)&LA[rr * LSTR + 4 * kq];
            float4 hh = *(const float4*)&LH[rr * LSTR + 4 * kq];
            ra[p] = fmaf(a.x, wr0.x, fmaf(a.y, wr0.y, fmaf(a.z, wr1.x, fmaf(a.w, wr1.y, ra[p]))));
            ra[p] = fmaf(hh.x, vr0.x, fmaf(hh.y, vr0.y, fmaf(hh.z, vr1.x, fmaf(hh.w, vr1.y, ra[p]))));
            za[p] = fmaf(a.x, wz0.x, fmaf(a.y, wz0.y, fmaf(a.z, wz1.x, fmaf(a.w, wz1.y, za[p]))));
            za[p] = fmaf(hh.x, vz0.x, fmaf(hh.y, vz0.y, fmaf(hh.z, vz1.x, fmaf(hh.w, vz1.y, za[p]))));
            ia[p] = fmaf(a.x, wi0.x, fmaf(a.y, wi0.y, fmaf(a.z, wi1.x, fmaf(a.w, wi1.y, ia[p]))));
            ha[p] = fmaf(hh.x, vn0.x, fmaf(hh.y, vn0.y, fmaf(hh.z, vn1.x, fmaf(hh.w, vn1.y, ha[p]))));
        }
    }
#pragma unroll
    for (int p = 0; p < 8; ++p) {
        int n = n0 + w8 + p;
        float r = 1.f / (1.f + __expf(-ra[p]));
        float z = 1.f / (1.f + __expf(-za[p]));
        float nx = ia[p] + r * ha[p];
        float tnh = 1.f - 2.f / (1.f + __expf(2.f * nx));  // tanh, overflow-safe
        float hn = (1.f - z) * tnh + z * LH[(w8 + p) * LSTR + lane];
        if (n < N) {
            size_t idx = (size_t)n * D + lane;
            if (houtb) houtb[idx] = __bfloat16_as_ushort(__float2bfloat16(hn));
            else if (flags[0]) ((float*)dout)[idx] = hn;
            else ((bf16*)dout)[idx] = __float2bfloat16(hn);
        }
    }
}

extern "C" void kernel_launch(void* const* d_in, const int* in_sizes, int n_in,
                              void* d_out, int out_size, void* d_ws, size_t ws_size,
                              hipStream_t stream) {
    const void* x   = d_in[0];
    const int*  ei  = (const int*)d_in[1];
    const void* Wnt = d_in[4];
    const void* bnt = d_in[5];
    const void* Wt  = d_in[6];   // [3,64,64]
    const void* Wih = d_in[7];   // [192,64]
    const void* Whh = d_in[8];
    const void* bih = d_in[9];
    const void* bhh = d_in[10];

    int N = in_sizes[0] / 6;
    int E = in_sizes[1] / 2;
    int ND = N * D;

    // Workspace (~26 MB). Order chosen so WCT/htA are 16B-aligned:
    // flags(256B) | WCT | WTh | B | htA | htB | cnt(N) | novf(1) | ss16(N*64 u16) | ovf(2E int)
    int* flags = (int*)d_ws;
    float* WCT = (float*)((char*)d_ws + 256);    // 36864 floats, 16B-aligned
    float* WTh = WCT + N_WCT;                    // 12288
    float* B   = WTh + N_WTH;                    // 384
    u16* htA = (u16*)(B + N_B);                  // byte 198400: 16B-aligned
    u16* htB = htA + ND;
    int* cnt  = (int*)(htB + ND);
    int* novf = cnt + N;
    u16* ss16 = (u16*)(novf + 1);
    int* ovf  = (int*)(ss16 + (size_t)N * 64);

    int NT_BLK = (ND + 255) / 256;
    int WC_BLK = (N_WCT + N_WTH + N_B + 255) / 256;
    int FI_BLK = (E + 255) / 256;

    hipMemsetAsync(cnt, 0, (size_t)(N + 1) * sizeof(int), stream);
    detect_kernel<<<1, 256, 0, stream>>>(x, ei, flags);
    prep_all<<<NT_BLK + WC_BLK + FI_BLK, 256, 0, stream>>>(flags, x, Wnt, bnt, Wt, Wih, Whh,
                                                           bih, bhh, htA, WCT, WTh, B,
                                                           ei, cnt, ss16, novf, ovf,
                                                           E, N, NT_BLK, WC_BLK);

    u16* hcur = htA;
    u16* hnxt = htB;
    for (int layer = 0; layer < 3; ++layer) {
        bool last = (layer == 2);
        layer_fused<<<(N + NPB - 1) / NPB, 256, 0, stream>>>(flags, hcur, cnt, ss16, novf, ovf,
                                                             WCT + layer * 12288, WTh, B,
                                                             last ? nullptr : hnxt,
                                                             last ? d_out : nullptr, N);
        u16* t = hcur; hcur = hnxt; hnxt = t;
    }
}

// Round 2
// 345.167 us; speedup vs baseline: 1.1887x; 1.1860x over previous
//
#include <hip/hip_runtime.h>
#include <hip/hip_bf16.h>
#include <stdint.h>

#define D 64
typedef __hip_bfloat16 bf16;
typedef unsigned short u16;
typedef __attribute__((ext_vector_type(8))) short bf16x8;
typedef __attribute__((ext_vector_type(4))) float f32x4;

__device__ __forceinline__ float bf2f(u16 u) { return __uint_as_float(((uint32_t)u) << 16); }
__device__ __forceinline__ u16 f2bf(float f) { return __bfloat16_as_ushort(__float2bfloat16(f)); }

template <bool F32>
__device__ __forceinline__ float ld(const void* p, int i) {
    if constexpr (F32) return ((const float*)p)[i];
    else return bf2f(((const u16*)p)[i]);
}

// ---- dtype oracle (proven): flags[0]=1 -> fp32 floats; flags[1]=1 -> int32 idx ----
__global__ __launch_bounds__(256) void detect_kernel(const void* x, const int* ei, int* flags) {
    __shared__ float smax[256];
    __shared__ int sor[256];
    int t = threadIdx.x;
    const u16* xs = (const u16*)x;
    float mx = 0.f;
#pragma unroll
    for (int i = 0; i < 16; ++i) {
        float a = fabsf(bf2f(xs[t * 16 + i]));
        if (!(a == a)) a = 1e30f;
        mx = fmaxf(mx, a);
    }
    int any = 0;
#pragma unroll
    for (int i = 0; i < 8; ++i) any |= ei[2 * (t * 8 + i) + 1];
    smax[t] = mx; sor[t] = any;
    __syncthreads();
    for (int s = 128; s > 0; s >>= 1) {
        if (t < s) { smax[t] = fmaxf(smax[t], smax[t + s]); sor[t] |= sor[t + s]; }
        __syncthreads();
    }
    if (t == 0) { flags[0] = (smax[0] > 1000.f) ? 1 : 0; flags[1] = (sor[0] != 0) ? 1 : 0; }
}

// ---- prep_all: nt (h0 -> bf16 table) + combined weights (bf16 hi/lo) + bucket fill ----
//  WCB[l][r][k] = sum_j W_l[k][j] * Wih[r][j]  stored r-major [192][64] as bf16 hi + lo
//  WVB[r][k]    = Whh[r][k]                    stored r-major [192][64] as bf16 hi + lo
//  B[0..191]=bih, B[192..383]=bhh (fp32)
#define N_WCT 36864
#define N_WTH 12288
#define N_B   384
template <bool F32>
__device__ __forceinline__ void nt_body(const void* x, const void* Wnt, const void* bnt,
                                        u16* ht, int N, int blk) {
    int gid = blk * 256 + threadIdx.x;
    if (gid >= N * D) return;
    int n = gid >> 6, c = gid & 63;
    float acc = ld<F32>(bnt, c);
#pragma unroll
    for (int k = 0; k < 6; ++k)
        acc = fmaf(ld<F32>(x, n * 6 + k), ld<F32>(Wnt, c * 6 + k), acc);
    ht[gid] = f2bf(fmaxf(acc, 0.f));
}
template <bool F32>
__device__ __forceinline__ void wc_body(const void* W, const void* Wih, const void* Whh,
                                        const void* bih, const void* bhh,
                                        u16* WCh, u16* WCl, u16* WVh, u16* WVl,
                                        float* B, int blk) {
    int i = blk * 256 + threadIdx.x;
    if (i < N_WCT) {
        int l = i / 12288, rem = i % 12288, k = rem / 192, r = rem % 192;
        float acc = 0.f;
#pragma unroll 8
        for (int j = 0; j < 64; ++j)
            acc = fmaf(ld<F32>(W, l * 4096 + k * 64 + j), ld<F32>(Wih, r * 64 + j), acc);
        u16 hi = f2bf(acc);
        WCh[l * 12288 + r * 64 + k] = hi;
        WCl[l * 12288 + r * 64 + k] = f2bf(acc - bf2f(hi));
    } else if (i < N_WCT + N_WTH) {
        int rem = i - N_WCT;
        int k = rem / 192, r = rem % 192;
        float v = ld<F32>(Whh, r * 64 + k);
        u16 hi = f2bf(v);
        WVh[r * 64 + k] = hi;
        WVl[r * 64 + k] = f2bf(v - bf2f(hi));
    } else if (i < N_WCT + N_WTH + N_B) {
        int rem = i - N_WCT - N_WTH;
        B[rem] = (rem < 192) ? ld<F32>(bih, rem) : ld<F32>(bhh, rem - 192);
    }
}
__global__ __launch_bounds__(256) void prep_all(const int* __restrict__ flags,
                                                const void* x, const void* Wnt, const void* bnt,
                                                const void* W, const void* Wih, const void* Whh,
                                                const void* bih, const void* bhh,
                                                u16* ht, u16* WCh, u16* WCl, u16* WVh, u16* WVl,
                                                float* B,
                                                const int* __restrict__ ei, int* __restrict__ cnt,
                                                u16* __restrict__ ss16, int* __restrict__ novf,
                                                int* __restrict__ ovf,
                                                int E, int N, int NT_BLK, int WC_BLK) {
    int b = blockIdx.x;
    if (b < NT_BLK) {
        if (flags[0]) nt_body<true>(x, Wnt, bnt, ht, N, b);
        else          nt_body<false>(x, Wnt, bnt, ht, N, b);
    } else if (b < NT_BLK + WC_BLK) {
        if (flags[0]) wc_body<true>(W, Wih, Whh, bih, bhh, WCh, WCl, WVh, WVl, B, b - NT_BLK);
        else          wc_body<false>(W, Wih, Whh, bih, bhh, WCh, WCl, WVh, WVl, B, b - NT_BLK);
    } else {
        int i = (b - NT_BLK - WC_BLK) * 256 + threadIdx.x;
        if (i >= E) return;
        int src, dst;
        if (flags[1]) { src = ei[i];     dst = ei[E + i]; }
        else          { src = ei[2 * i]; dst = ei[2 * (E + i)]; }
        if ((unsigned)src >= (unsigned)N || (unsigned)dst >= (unsigned)N) return;
        int pos = atomicAdd(&cnt[dst], 1);
        if (pos < 64) ss16[(size_t)dst * 64 + pos] = (u16)src;
        else { int o = atomicAdd(novf, 1); ovf[2 * o] = dst; ovf[2 * o + 1] = src; }
    }
}

// ======= fused layer: 16 nodes/block, gather on VALU, GRU gates on MFMA =======
// Gate GEMMs: gi = agg @ WC, gh = h @ WhhT via mfma_f32_16x16x32_bf16.
// Precision: agg split hi/lo bf16 (3 passes vs WC hi + hi pass vs WC lo);
//            h is exactly bf16 -> 2 passes vs WV hi/lo. Missing lo*lo ~1e-6.
// Wave w owns output channels [16w,16w+16) via ntiles {w, w+4, w+8} = r,z,n gates.
// A/H tiles in LDS [16][64] bf16 with XOR swizzle (byte ^= (row&7)<<4) ->
// conflict-free ds_read_b128 fragment loads (k contiguous per lane group).
#define NPB 16
#define LSTR 68
__global__ __launch_bounds__(256) void layer_fused(const int* __restrict__ flags,
                                                   const u16* __restrict__ ht,
                                                   const int* __restrict__ cnt,
                                                   const u16* __restrict__ ss16,
                                                   const int* __restrict__ novf,
                                                   const int* __restrict__ ovf,
                                                   const u16* __restrict__ WCh,
                                                   const u16* __restrict__ WCl,
                                                   const u16* __restrict__ WVh,
                                                   const u16* __restrict__ WVl,
                                                   const float* __restrict__ B,
                                                   u16* __restrict__ houtb,
                                                   void* __restrict__ dout,
                                                   int N) {
    __shared__ alignas(16) float LA[NPB * LSTR];
    __shared__ alignas(16) float LH[NPB * LSTR];
    __shared__ alignas(16) u16 Ahi[NPB * 64];
    __shared__ alignas(16) u16 Alo[NPB * 64];
    __shared__ alignas(16) u16 Hb[NPB * 64];
    int t = threadIdx.x;
    int n0 = blockIdx.x * NPB;
    int lane = t & 63;
    int w = t >> 6;
    int w4 = w * 4;

    {   // stage own h rows: LH fp32 (epilogue) + Hb bf16 tile (MFMA A, swizzled)
        if (t < 128) {
            int row = t >> 3, c = (t & 7) * 8;
            bool v = (n0 + row) < N;
            uint4 vh = make_uint4(0u, 0u, 0u, 0u);
            if (v) vh = *(const uint4*)(ht + (size_t)(n0 + row) * D + c);
            float4 f0, f1;
            f0.x = bf2f((u16)(vh.x & 0xffff)); f0.y = bf2f((u16)(vh.x >> 16));
            f0.z = bf2f((u16)(vh.y & 0xffff)); f0.w = bf2f((u16)(vh.y >> 16));
            f1.x = bf2f((u16)(vh.z & 0xffff)); f1.y = bf2f((u16)(vh.z >> 16));
            f1.z = bf2f((u16)(vh.w & 0xffff)); f1.w = bf2f((u16)(vh.w >> 16));
            *(float4*)&LH[row * LSTR + c]     = f0;
            *(float4*)&LH[row * LSTR + c + 4] = f1;
            *(uint4*)((char*)Hb + row * 128 + ((c * 2) ^ ((row & 7) << 4))) = vh;
        }
    }

    // ---- gather: lane-parallel index preload, shfl broadcast, 16-deep batches ----
    int dg[4]; int iv[4];
#pragma unroll
    for (int p = 0; p < 4; ++p) {
        int n = n0 + w4 + p;
        dg[p] = 0; iv[p] = 0;
        if (n < N) {
            int c = cnt[n]; dg[p] = (c > 64) ? 64 : c;
            iv[p] = (int)ss16[(size_t)n * 64 + lane];
        }
    }
#pragma unroll
    for (int p = 0; p < 4; ++p) {
        float acc = 0.f;
        int dgp = dg[p], ivp = iv[p];
        int j = 0;
        for (; j + 15 < dgp; j += 16) {
            int ix[16]; float a[16];
#pragma unroll
            for (int q = 0; q < 16; ++q) ix[q] = __shfl(ivp, j + q);
#pragma unroll
            for (int q = 0; q < 16; ++q) a[q] = bf2f(ht[(size_t)ix[q] * D + lane]);
            acc += (((a[0] + a[1]) + (a[2] + a[3])) + ((a[4] + a[5]) + (a[6] + a[7])))
                 + (((a[8] + a[9]) + (a[10] + a[11])) + ((a[12] + a[13]) + (a[14] + a[15])));
        }
        for (; j + 7 < dgp; j += 8) {
            int ix[8]; float a[8];
#pragma unroll
            for (int q = 0; q < 8; ++q) ix[q] = __shfl(ivp, j + q);
#pragma unroll
            for (int q = 0; q < 8; ++q) a[q] = bf2f(ht[(size_t)ix[q] * D + lane]);
            acc += ((a[0] + a[1]) + (a[2] + a[3])) + ((a[4] + a[5]) + (a[6] + a[7]));
        }
        for (; j + 3 < dgp; j += 4) {
            int ix[4]; float a[4];
#pragma unroll
            for (int q = 0; q < 4; ++q) ix[q] = __shfl(ivp, j + q);
#pragma unroll
            for (int q = 0; q < 4; ++q) a[q] = bf2f(ht[(size_t)ix[q] * D + lane]);
            acc += (a[0] + a[1]) + (a[2] + a[3]);
        }
        for (; j < dgp; ++j) acc += bf2f(ht[(size_t)__shfl(ivp, j) * D + lane]);
        LA[(w4 + p) * LSTR + lane] = acc;
    }
    __syncthreads();
    {   // exact overflow drain (novf==0 in practice)
        int nv = novf[0];
        if (nv > 0) {
            for (int o = w; o < nv; o += 4) {
                int dst = ovf[2 * o];
                if (dst >= n0 && dst < n0 + NPB) {
                    int src = ovf[2 * o + 1];
                    atomicAdd(&LA[(dst - n0) * LSTR + lane], bf2f(ht[(size_t)src * D + lane]));
                }
            }
        }
    }
    __syncthreads();
    {   // convert agg fp32 -> Ahi/Alo bf16 tiles (swizzled 8B stores)
        int row = t >> 4, c = (t & 15) * 4;
        float4 v = *(const float4*)&LA[row * LSTR + c];
        u16 h0 = f2bf(v.x), h1 = f2bf(v.y), h2 = f2bf(v.z), h3 = f2bf(v.w);
        uint2 hh, ll;
        hh.x = (uint32_t)h0 | ((uint32_t)h1 << 16);
        hh.y = (uint32_t)h2 | ((uint32_t)h3 << 16);
        ll.x = (uint32_t)f2bf(v.x - bf2f(h0)) | ((uint32_t)f2bf(v.y - bf2f(h1)) << 16);
        ll.y = (uint32_t)f2bf(v.z - bf2f(h2)) | ((uint32_t)f2bf(v.w - bf2f(h3)) << 16);
        int off = row * 128 + ((c * 2) ^ ((row & 7) << 4));
        *(uint2*)((char*)Ahi + off) = hh;
        *(uint2*)((char*)Alo + off) = ll;
    }
    __syncthreads();

    // ---- MFMA gate GEMMs ----
    int r = lane & 15, g = lane >> 4;
    int aoff0 = r * 128 + (((g * 16) + 0) ^ ((r & 7) << 4));
    int aoff1 = r * 128 + (((g * 16) + 64) ^ ((r & 7) << 4));
    bf16x8 aH0 = *(const bf16x8*)((const char*)Ahi + aoff0);
    bf16x8 aH1 = *(const bf16x8*)((const char*)Ahi + aoff1);
    bf16x8 aL0 = *(const bf16x8*)((const char*)Alo + aoff0);
    bf16x8 aL1 = *(const bf16x8*)((const char*)Alo + aoff1);
    bf16x8 hB0 = *(const bf16x8*)((const char*)Hb + aoff0);
    bf16x8 hB1 = *(const bf16x8*)((const char*)Hb + aoff1);

#define WFRAG(P, nt, ks) (*(const bf16x8*)((const char*)(P) + ((nt) * 16 + r) * 128 + (ks) * 64 + g * 16))
#define DO_TILE(nt, ai, ah) { \
    bf16x8 wch0 = WFRAG(WCh, nt, 0), wch1 = WFRAG(WCh, nt, 1); \
    bf16x8 wcl0 = WFRAG(WCl, nt, 0), wcl1 = WFRAG(WCl, nt, 1); \
    bf16x8 wvh0 = WFRAG(WVh, nt, 0), wvh1 = WFRAG(WVh, nt, 1); \
    bf16x8 wvl0 = WFRAG(WVl, nt, 0), wvl1 = WFRAG(WVl, nt, 1); \
    ai = __builtin_amdgcn_mfma_f32_16x16x32_bf16(aH0, wch0, ai, 0, 0, 0); \
    ai = __builtin_amdgcn_mfma_f32_16x16x32_bf16(aH1, wch1, ai, 0, 0, 0); \
    ai = __builtin_amdgcn_mfma_f32_16x16x32_bf16(aL0, wch0, ai, 0, 0, 0); \
    ai = __builtin_amdgcn_mfma_f32_16x16x32_bf16(aL1, wch1, ai, 0, 0, 0); \
    ai = __builtin_amdgcn_mfma_f32_16x16x32_bf16(aH0, wcl0, ai, 0, 0, 0); \
    ai = __builtin_amdgcn_mfma_f32_16x16x32_bf16(aH1, wcl1, ai, 0, 0, 0); \
    ah = __builtin_amdgcn_mfma_f32_16x16x32_bf16(hB0, wvh0, ah, 0, 0, 0); \
    ah = __builtin_amdgcn_mfma_f32_16x16x32_bf16(hB1, wvh1, ah, 0, 0, 0); \
    ah = __builtin_amdgcn_mfma_f32_16x16x32_bf16(hB0, wvl0, ah, 0, 0, 0); \
    ah = __builtin_amdgcn_mfma_f32_16x16x32_bf16(hB1, wvl1, ah, 0, 0, 0); }

    f32x4 air = {0.f, 0.f, 0.f, 0.f}, aiz = air, ain = air;
    f32x4 ahr = air, ahz = air, ahn = air;
    DO_TILE(w, air, ahr);
    DO_TILE(w + 4, aiz, ahz);
    DO_TILE(w + 8, ain, ahn);

    // ---- epilogue: lane holds (4 nodes) x (1 channel); all gates in registers ----
    {
        int ch = w * 16 + r;
        float br = B[ch] + B[192 + ch];
        float bz = B[64 + ch] + B[256 + ch];
        float bi = B[128 + ch];
        float bh = B[320 + ch];
        int nb = g * 4;
#pragma unroll
        for (int j = 0; j < 4; ++j) {
            float gr = air[j] + ahr[j] + br;
            float gz = aiz[j] + ahz[j] + bz;
            float rr = 1.f / (1.f + __expf(-gr));
            float zz = 1.f / (1.f + __expf(-gz));
            float nx = ain[j] + bi + rr * (ahn[j] + bh);
            float th = 1.f - 2.f / (1.f + __expf(2.f * nx));  // tanh, overflow-safe
            float hold = LH[(nb + j) * LSTR + ch];
            LA[(nb + j) * LSTR + ch] = (1.f - zz) * th + zz * hold;
        }
    }
    __syncthreads();
    // ---- coalesced store-out ----
    if (t < 128) {
        int row = t >> 3, c = (t & 7) * 8;
        int n = n0 + row;
        if (n < N) {
            float4 v0 = *(const float4*)&LA[row * LSTR + c];
            float4 v1 = *(const float4*)&LA[row * LSTR + c + 4];
            size_t idx = (size_t)n * D + c;
            if (houtb || !flags[0]) {
                uint4 o;
                o.x = (uint32_t)f2bf(v0.x) | ((uint32_t)f2bf(v0.y) << 16);
                o.y = (uint32_t)f2bf(v0.z) | ((uint32_t)f2bf(v0.w) << 16);
                o.z = (uint32_t)f2bf(v1.x) | ((uint32_t)f2bf(v1.y) << 16);
                o.w = (uint32_t)f2bf(v1.z) | ((uint32_t)f2bf(v1.w) << 16);
                if (houtb) *(uint4*)(houtb + idx) = o;
                else       *(uint4*)((u16*)dout + idx) = o;
            } else {
                *(float4*)((float*)dout + idx)     = v0;
                *(float4*)((float*)dout + idx + 4) = v1;
            }
        }
    }
}

extern "C" void kernel_launch(void* const* d_in, const int* in_sizes, int n_in,
                              void* d_out, int out_size, void* d_ws, size_t ws_size,
                              hipStream_t stream) {
    const void* x   = d_in[0];
    const int*  ei  = (const int*)d_in[1];
    const void* Wnt = d_in[4];
    const void* bnt = d_in[5];
    const void* Wt  = d_in[6];   // [3,64,64]
    const void* Wih = d_in[7];   // [192,64]
    const void* Whh = d_in[8];
    const void* bih = d_in[9];
    const void* bhh = d_in[10];

    int N = in_sizes[0] / 6;
    int E = in_sizes[1] / 2;
    int ND = N * D;

    // Workspace (~26 MB):
    // flags(256B) | B(f32 384) | WCh | WCl | WVh | WVl | htA | htB | cnt(N) | novf | ss16 | ovf
    int* flags = (int*)d_ws;
    float* B   = (float*)((char*)d_ws + 256);
    u16* WCh = (u16*)(B + N_B);          // 3*192*64 bf16
    u16* WCl = WCh + N_WCT;
    u16* WVh = WCl + N_WCT;              // 192*64 bf16
    u16* WVl = WVh + N_WTH;
    u16* htA = WVl + N_WTH;              // byte 198400: 16B-aligned
    u16* htB = htA + ND;
    int* cnt  = (int*)(htB + ND);
    int* novf = cnt + N;
    u16* ss16 = (u16*)(novf + 1);
    int* ovf  = (int*)(ss16 + (size_t)N * 64);

    int NT_BLK = (ND + 255) / 256;
    int WC_BLK = (N_WCT + N_WTH + N_B + 255) / 256;
    int FI_BLK = (E + 255) / 256;

    hipMemsetAsync(cnt, 0, (size_t)(N + 1) * sizeof(int), stream);
    detect_kernel<<<1, 256, 0, stream>>>(x, ei, flags);
    prep_all<<<NT_BLK + WC_BLK + FI_BLK, 256, 0, stream>>>(flags, x, Wnt, bnt, Wt, Wih, Whh,
                                                           bih, bhh, htA, WCh, WCl, WVh, WVl, B,
                                                           ei, cnt, ss16, novf, ovf,
                                                           E, N, NT_BLK, WC_BLK);

    u16* hcur = htA;
    u16* hnxt = htB;
    for (int layer = 0; layer < 3; ++layer) {
        bool last = (layer == 2);
        layer_fused<<<(N + NPB - 1) / NPB, 256, 0, stream>>>(flags, hcur, cnt, ss16, novf, ovf,
                                                             WCh + layer * 12288, WCl + layer * 12288,
                                                             WVh, WVl, B,
                                                             last ? nullptr : hnxt,
                                                             last ? d_out : nullptr, N);
        u16* t = hcur; hcur = hnxt; hnxt = t;
    }
}

// Round 4
// 313.402 us; speedup vs baseline: 1.3092x; 1.1014x over previous
//
#include <hip/hip_runtime.h>
#include <hip/hip_bf16.h>
#include <stdint.h>

#define D 64
typedef __hip_bfloat16 bf16;
typedef unsigned short u16;
typedef __attribute__((ext_vector_type(8))) short bf16x8;
typedef __attribute__((ext_vector_type(4))) float f32x4;

__device__ __forceinline__ float bf2f(u16 u) { return __uint_as_float(((uint32_t)u) << 16); }
__device__ __forceinline__ u16 f2bf(float f) { return __bfloat16_as_ushort(__float2bfloat16(f)); }

template <bool F32>
__device__ __forceinline__ float ld(const void* p, int i) {
    if constexpr (F32) return ((const float*)p)[i];
    else return bf2f(((const u16*)p)[i]);
}

// ---- dtype oracle (proven): flags[0]=1 -> fp32 floats; flags[1]=1 -> int32 idx ----
__global__ __launch_bounds__(256) void detect_kernel(const void* x, const int* ei, int* flags) {
    __shared__ float smax[256];
    __shared__ int sor[256];
    int t = threadIdx.x;
    const u16* xs = (const u16*)x;
    float mx = 0.f;
#pragma unroll
    for (int i = 0; i < 16; ++i) {
        float a = fabsf(bf2f(xs[t * 16 + i]));
        if (!(a == a)) a = 1e30f;
        mx = fmaxf(mx, a);
    }
    int any = 0;
#pragma unroll
    for (int i = 0; i < 8; ++i) any |= ei[2 * (t * 8 + i) + 1];
    smax[t] = mx; sor[t] = any;
    __syncthreads();
    for (int s = 128; s > 0; s >>= 1) {
        if (t < s) { smax[t] = fmaxf(smax[t], smax[t + s]); sor[t] |= sor[t + s]; }
        __syncthreads();
    }
    if (t == 0) { flags[0] = (smax[0] > 1000.f) ? 1 : 0; flags[1] = (sor[0] != 0) ? 1 : 0; }
}

// ---- convert_edges: ei (i64/i32) -> packed u32 (src16 | dst16<<16); sentinel 0xFFFFFFFF ----
__global__ __launch_bounds__(256) void convert_edges(const int* __restrict__ flags,
                                                     const int* __restrict__ ei,
                                                     uint32_t* __restrict__ pe, int E, int N) {
    int i0 = blockIdx.x * 1024 + threadIdx.x;
    bool i32 = flags[1] != 0;
#pragma unroll
    for (int u = 0; u < 4; ++u) {
        int i = i0 + u * 256;
        if (i < E) {
            int src, dst;
            if (i32) { src = ei[i];     dst = ei[E + i]; }
            else     { src = ei[2 * i]; dst = ei[2 * (E + i)]; }
            uint32_t v;
            if ((unsigned)src >= (unsigned)N || (unsigned)dst >= (unsigned)N) v = 0xFFFFFFFFu;
            else v = (uint32_t)(u16)src | ((uint32_t)dst << 16);
            pe[i] = v;
        }
    }
}

// ---- prep_all: nt (h0 -> bf16 table) + combined weights (bf16 hi/lo) + XCD-sharded fill ----
//  Fill: 8 blocks per edge-slice; block keeps edges with (dst>>4)&7 == blockIdx&7.
//  b&7 over 8 consecutive blocks is a bijection onto {0..7} -> exact coverage regardless
//  of dispatch mapping; XCD-locality of cnt/ss16 lines is the perf heuristic (G16-safe).
#define N_WCT 36864
#define N_WTH 12288
#define N_B   384
template <bool F32>
__device__ __forceinline__ void nt_body(const void* x, const void* Wnt, const void* bnt,
                                        u16* ht, int N, int blk) {
    int gid = blk * 256 + threadIdx.x;
    if (gid >= N * D) return;
    int n = gid >> 6, c = gid & 63;
    float acc = ld<F32>(bnt, c);
#pragma unroll
    for (int k = 0; k < 6; ++k)
        acc = fmaf(ld<F32>(x, n * 6 + k), ld<F32>(Wnt, c * 6 + k), acc);
    ht[gid] = f2bf(fmaxf(acc, 0.f));
}
template <bool F32>
__device__ __forceinline__ void wc_body(const void* W, const void* Wih, const void* Whh,
                                        const void* bih, const void* bhh,
                                        u16* WCh, u16* WCl, u16* WVh, u16* WVl,
                                        float* B, int blk) {
    int i = blk * 256 + threadIdx.x;
    if (i < N_WCT) {
        int l = i / 12288, rem = i % 12288, k = rem / 192, r = rem % 192;
        float acc = 0.f;
#pragma unroll 8
        for (int j = 0; j < 64; ++j)
            acc = fmaf(ld<F32>(W, l * 4096 + k * 64 + j), ld<F32>(Wih, r * 64 + j), acc);
        u16 hi = f2bf(acc);
        WCh[l * 12288 + r * 64 + k] = hi;
        WCl[l * 12288 + r * 64 + k] = f2bf(acc - bf2f(hi));
    } else if (i < N_WCT + N_WTH) {
        int rem = i - N_WCT;
        int k = rem / 192, r = rem % 192;
        float v = ld<F32>(Whh, r * 64 + k);
        u16 hi = f2bf(v);
        WVh[r * 64 + k] = hi;
        WVl[r * 64 + k] = f2bf(v - bf2f(hi));
    } else if (i < N_WCT + N_WTH + N_B) {
        int rem = i - N_WCT - N_WTH;
        B[rem] = (rem < 192) ? ld<F32>(bih, rem) : ld<F32>(bhh, rem - 192);
    }
}
__global__ __launch_bounds__(256) void prep_all(const int* __restrict__ flags,
                                                const void* x, const void* Wnt, const void* bnt,
                                                const void* W, const void* Wih, const void* Whh,
                                                const void* bih, const void* bhh,
                                                u16* ht, u16* WCh, u16* WCl, u16* WVh, u16* WVl,
                                                float* B,
                                                const uint32_t* __restrict__ pe,
                                                int* __restrict__ cnt,
                                                u16* __restrict__ ss16, int* __restrict__ novf,
                                                int* __restrict__ ovf,
                                                int E, int N, int NT_BLK, int WC_BLK, int EPS) {
    int b = blockIdx.x;
    if (b < NT_BLK) {
        if (flags[0]) nt_body<true>(x, Wnt, bnt, ht, N, b);
        else          nt_body<false>(x, Wnt, bnt, ht, N, b);
    } else if (b < NT_BLK + WC_BLK) {
        if (flags[0]) wc_body<true>(W, Wih, Whh, bih, bhh, WCh, WCl, WVh, WVl, B, b - NT_BLK);
        else          wc_body<false>(W, Wih, Whh, bih, bhh, WCh, WCl, WVh, WVl, B, b - NT_BLK);
    } else {
        int bf = b - NT_BLK - WC_BLK;
        unsigned shard = (unsigned)(b & 7);      // bijection per 8-block group; == XCD id under RR
        int beg = (bf >> 3) * EPS;
        int end = beg + EPS; if (end > E) end = E;
        for (int i = beg + (int)threadIdx.x; i < end; i += 256) {
            uint32_t e = pe[i];
            int dst = (int)(e >> 16);
            if ((((unsigned)dst >> 4) & 7u) != shard) continue;  // one XCD per cnt/ss16 line
            if (dst >= N) continue;                              // sentinel filtered here
            int src = (int)(e & 0xffffu);
            int pos = atomicAdd(&cnt[dst], 1);
            if (pos < 64) ss16[(size_t)dst * 64 + pos] = (u16)src;
            else {
                int o = atomicAdd(novf, 1);
                if (o < E) { ovf[2 * o] = dst; ovf[2 * o + 1] = src; }  // hardened vs OOB
            }
        }
    }
}

// ======= fused layer: 16 nodes/block; 4-node-interleaved masked gather; gates on MFMA =======
#define NPB 16
#define LSTR 68

// stage-A/B load macro: 16 masked row-loads for node P starting at neighbor J into A[16].
// dg[P] is wave-uniform -> masks are scalar compares; invalid slots clamp to hot row 0
// BEFORE the load (no OOB), value masked to 0 after.
#define GLOAD(A, P, J) \
    _Pragma("unroll") for (int q = 0; q < 16; ++q) { \
        int ix_ = __shfl(iv[P], (J) + q); \
        bool vq_ = ((J) + q) < dg[P]; \
        ix_ = vq_ ? ix_ : 0; \
        float tv_ = bf2f(ht[(size_t)ix_ * D + lane]); \
        A[q] = vq_ ? tv_ : 0.f; }
#define GSUM(A) (((((A)[0]+(A)[1])+((A)[2]+(A)[3]))+(((A)[4]+(A)[5])+((A)[6]+(A)[7]))) \
               + ((((A)[8]+(A)[9])+((A)[10]+(A)[11]))+(((A)[12]+(A)[13])+((A)[14]+(A)[15]))))

__global__ __launch_bounds__(256, 3) void layer_fused(const int* __restrict__ flags,
                                                   const u16* __restrict__ ht,
                                                   const int* __restrict__ cnt,
                                                   const u16* __restrict__ ss16,
                                                   const int* __restrict__ novf,
                                                   const int* __restrict__ ovf,
                                                   const u16* __restrict__ WCh,
                                                   const u16* __restrict__ WCl,
                                                   const u16* __restrict__ WVh,
                                                   const u16* __restrict__ WVl,
                                                   const float* __restrict__ B,
                                                   u16* __restrict__ houtb,
                                                   void* __restrict__ dout,
                                                   int N) {
    __shared__ alignas(16) float LA[NPB * LSTR];
    __shared__ alignas(16) float LH[NPB * LSTR];
    __shared__ alignas(16) u16 Ahi[NPB * 64];
    __shared__ alignas(16) u16 Alo[NPB * 64];
    __shared__ alignas(16) u16 Hb[NPB * 64];
    int t = threadIdx.x;
    int n0 = blockIdx.x * NPB;
    int lane = t & 63;
    int w = t >> 6;
    int w4 = w * 4;

    {   // stage own h rows: LH fp32 (epilogue) + Hb bf16 tile (MFMA A, swizzled)
        if (t < 128) {
            int row = t >> 3, c = (t & 7) * 8;
            bool v = (n0 + row) < N;
            uint4 vh = make_uint4(0u, 0u, 0u, 0u);
            if (v) vh = *(const uint4*)(ht + (size_t)(n0 + row) * D + c);
            float4 f0, f1;
            f0.x = bf2f((u16)(vh.x & 0xffff)); f0.y = bf2f((u16)(vh.x >> 16));
            f0.z = bf2f((u16)(vh.y & 0xffff)); f0.w = bf2f((u16)(vh.y >> 16));
            f1.x = bf2f((u16)(vh.z & 0xffff)); f1.y = bf2f((u16)(vh.z >> 16));
            f1.z = bf2f((u16)(vh.w & 0xffff)); f1.w = bf2f((u16)(vh.w >> 16));
            *(float4*)&LH[row * LSTR + c]     = f0;
            *(float4*)&LH[row * LSTR + c + 4] = f1;
            *(uint4*)((char*)Hb + row * 128 + ((c * 2) ^ ((row & 7) << 4))) = vh;
        }
    }

    // ---- gather: lane-parallel index preload; 4-node interleaved masked batches ----
    int dg[4]; int iv[4];
#pragma unroll
    for (int p = 0; p < 4; ++p) {
        int n = n0 + w4 + p;
        dg[p] = 0; iv[p] = 0;
        if (n < N) {
            int c = cnt[n]; dg[p] = (c > 64) ? 64 : c;
            iv[p] = (int)ss16[(size_t)n * 64 + lane];
        }
    }
    float acc0, acc1, acc2, acc3;
    {   // stage A: first <=16 neighbors of ALL 4 nodes -> 64 loads in flight
        float a0[16], a1[16], a2[16], a3[16];
        GLOAD(a0, 0, 0) GLOAD(a1, 1, 0) GLOAD(a2, 2, 0) GLOAD(a3, 3, 0)
        acc0 = GSUM(a0); acc1 = GSUM(a1); acc2 = GSUM(a2); acc3 = GSUM(a3);
    }
    // stage B: neighbors 16..31 (masked) + scalar tail 32..dg (P(dg>32) ~ 2e-4)
#define GTAIL(P, ACC) if (dg[P] > 16) { \
        float b_[16]; \
        GLOAD(b_, P, 16) \
        ACC += GSUM(b_); \
        for (int j = 32; j < dg[P]; ++j) \
            ACC += bf2f(ht[(size_t)__shfl(iv[P], j) * D + lane]); }
    GTAIL(0, acc0) GTAIL(1, acc1) GTAIL(2, acc2) GTAIL(3, acc3)
    LA[(w4 + 0) * LSTR + lane] = acc0;
    LA[(w4 + 1) * LSTR + lane] = acc1;
    LA[(w4 + 2) * LSTR + lane] = acc2;
    LA[(w4 + 3) * LSTR + lane] = acc3;
    __syncthreads();
    {   // exact overflow drain (novf==0 in practice)
        int nv = novf[0];
        if (nv > 0) {
            if (nv > (1 << 20)) nv = (1 << 20);
            for (int o = w; o < nv; o += 4) {
                int dst = ovf[2 * o];
                if (dst >= n0 && dst < n0 + NPB) {
                    int src = ovf[2 * o + 1];
                    atomicAdd(&LA[(dst - n0) * LSTR + lane], bf2f(ht[(size_t)src * D + lane]));
                }
            }
        }
    }
    __syncthreads();
    {   // convert agg fp32 -> Ahi/Alo bf16 tiles (swizzled 8B stores)
        int row = t >> 4, c = (t & 15) * 4;
        float4 v = *(const float4*)&LA[row * LSTR + c];
        u16 h0 = f2bf(v.x), h1 = f2bf(v.y), h2 = f2bf(v.z), h3 = f2bf(v.w);
        uint2 hh, llv;
        hh.x = (uint32_t)h0 | ((uint32_t)h1 << 16);
        hh.y = (uint32_t)h2 | ((uint32_t)h3 << 16);
        llv.x = (uint32_t)f2bf(v.x - bf2f(h0)) | ((uint32_t)f2bf(v.y - bf2f(h1)) << 16);
        llv.y = (uint32_t)f2bf(v.z - bf2f(h2)) | ((uint32_t)f2bf(v.w - bf2f(h3)) << 16);
        int off = row * 128 + ((c * 2) ^ ((row & 7) << 4));
        *(uint2*)((char*)Ahi + off) = hh;
        *(uint2*)((char*)Alo + off) = llv;
    }
    __syncthreads();

    // ---- MFMA gate GEMMs ----
    int r = lane & 15, g = lane >> 4;
    int aoff0 = r * 128 + (((g * 16) + 0) ^ ((r & 7) << 4));
    int aoff1 = r * 128 + (((g * 16) + 64) ^ ((r & 7) << 4));
    bf16x8 aH0 = *(const bf16x8*)((const char*)Ahi + aoff0);
    bf16x8 aH1 = *(const bf16x8*)((const char*)Ahi + aoff1);
    bf16x8 aL0 = *(const bf16x8*)((const char*)Alo + aoff0);
    bf16x8 aL1 = *(const bf16x8*)((const char*)Alo + aoff1);
    bf16x8 hB0 = *(const bf16x8*)((const char*)Hb + aoff0);
    bf16x8 hB1 = *(const bf16x8*)((const char*)Hb + aoff1);

#define WFRAG(P, nt, ks) (*(const bf16x8*)((const char*)(P) + ((nt) * 16 + r) * 128 + (ks) * 64 + g * 16))
#define DO_TILE(nt, ai, ah) { \
    bf16x8 wch0 = WFRAG(WCh, nt, 0), wch1 = WFRAG(WCh, nt, 1); \
    bf16x8 wcl0 = WFRAG(WCl, nt, 0), wcl1 = WFRAG(WCl, nt, 1); \
    bf16x8 wvh0 = WFRAG(WVh, nt, 0), wvh1 = WFRAG(WVh, nt, 1); \
    bf16x8 wvl0 = WFRAG(WVl, nt, 0), wvl1 = WFRAG(WVl, nt, 1); \
    ai = __builtin_amdgcn_mfma_f32_16x16x32_bf16(aH0, wch0, ai, 0, 0, 0); \
    ai = __builtin_amdgcn_mfma_f32_16x16x32_bf16(aH1, wch1, ai, 0, 0, 0); \
    ai = __builtin_amdgcn_mfma_f32_16x16x32_bf16(aL0, wch0, ai, 0, 0, 0); \
    ai = __builtin_amdgcn_mfma_f32_16x16x32_bf16(aL1, wch1, ai, 0, 0, 0); \
    ai = __builtin_amdgcn_mfma_f32_16x16x32_bf16(aH0, wcl0, ai, 0, 0, 0); \
    ai = __builtin_amdgcn_mfma_f32_16x16x32_bf16(aH1, wcl1, ai, 0, 0, 0); \
    ah = __builtin_amdgcn_mfma_f32_16x16x32_bf16(hB0, wvh0, ah, 0, 0, 0); \
    ah = __builtin_amdgcn_mfma_f32_16x16x32_bf16(hB1, wvh1, ah, 0, 0, 0); \
    ah = __builtin_amdgcn_mfma_f32_16x16x32_bf16(hB0, wvl0, ah, 0, 0, 0); \
    ah = __builtin_amdgcn_mfma_f32_16x16x32_bf16(hB1, wvl1, ah, 0, 0, 0); }

    f32x4 air = {0.f, 0.f, 0.f, 0.f}, aiz = air, ain = air;
    f32x4 ahr = air, ahz = air, ahn = air;
    DO_TILE(w, air, ahr);
    DO_TILE(w + 4, aiz, ahz);
    DO_TILE(w + 8, ain, ahn);

    // ---- epilogue: lane holds (4 nodes) x (1 channel); all gates in registers ----
    {
        int ch = w * 16 + r;
        float br = B[ch] + B[192 + ch];
        float bz = B[64 + ch] + B[256 + ch];
        float bi = B[128 + ch];
        float bh = B[320 + ch];
        int nb = g * 4;
#pragma unroll
        for (int j = 0; j < 4; ++j) {
            float gr = air[j] + ahr[j] + br;
            float gz = aiz[j] + ahz[j] + bz;
            float rr = 1.f / (1.f + __expf(-gr));
            float zz = 1.f / (1.f + __expf(-gz));
            float nx = ain[j] + bi + rr * (ahn[j] + bh);
            float th = 1.f - 2.f / (1.f + __expf(2.f * nx));  // tanh, overflow-safe
            float hold = LH[(nb + j) * LSTR + ch];
            LA[(nb + j) * LSTR + ch] = (1.f - zz) * th + zz * hold;
        }
    }
    __syncthreads();
    // ---- coalesced store-out ----
    if (t < 128) {
        int row = t >> 3, c = (t & 7) * 8;
        int n = n0 + row;
        if (n < N) {
            float4 v0 = *(const float4*)&LA[row * LSTR + c];
            float4 v1 = *(const float4*)&LA[row * LSTR + c + 4];
            size_t idx = (size_t)n * D + c;
            if (houtb || !flags[0]) {
                uint4 o;
                o.x = (uint32_t)f2bf(v0.x) | ((uint32_t)f2bf(v0.y) << 16);
                o.y = (uint32_t)f2bf(v0.z) | ((uint32_t)f2bf(v0.w) << 16);
                o.z = (uint32_t)f2bf(v1.x) | ((uint32_t)f2bf(v1.y) << 16);
                o.w = (uint32_t)f2bf(v1.z) | ((uint32_t)f2bf(v1.w) << 16);
                if (houtb) *(uint4*)(houtb + idx) = o;
                else       *(uint4*)((u16*)dout + idx) = o;
            } else {
                *(float4*)((float*)dout + idx)     = v0;
                *(float4*)((float*)dout + idx + 4) = v1;
            }
        }
    }
}

extern "C" void kernel_launch(void* const* d_in, const int* in_sizes, int n_in,
                              void* d_out, int out_size, void* d_ws, size_t ws_size,
                              hipStream_t stream) {
    const void* x   = d_in[0];
    const int*  ei  = (const int*)d_in[1];
    const void* Wnt = d_in[4];
    const void* bnt = d_in[5];
    const void* Wt  = d_in[6];   // [3,64,64]
    const void* Wih = d_in[7];   // [192,64]
    const void* Whh = d_in[8];
    const void* bih = d_in[9];
    const void* bhh = d_in[10];

    int N = in_sizes[0] / 6;
    int E = in_sizes[1] / 2;
    int ND = N * D;

    // Workspace (~29 MB, within proven 38.4 MB):
    // flags(256B) | B | WCh | WCl | WVh | WVl | htA | htB | cnt(N) | novf | ss16 | ovf(2E) | pe(E)
    int* flags = (int*)d_ws;
    float* B   = (float*)((char*)d_ws + 256);
    u16* WCh = (u16*)(B + N_B);          // 3*192*64 bf16
    u16* WCl = WCh + N_WCT;
    u16* WVh = WCl + N_WCT;              // 192*64 bf16
    u16* WVl = WVh + N_WTH;
    u16* htA = WVl + N_WTH;              // 16B-aligned
    u16* htB = htA + ND;
    int* cnt  = (int*)(htB + ND);
    int* novf = cnt + N;
    u16* ss16 = (u16*)(novf + 1);
    int* ovf  = (int*)(ss16 + (size_t)N * 64);
    uint32_t* pe = (uint32_t*)(ovf + 2 * (size_t)E);

    int NT_BLK = (ND + 255) / 256;
    int WC_BLK = (N_WCT + N_WTH + N_B + 255) / 256;
    int FS = (E + 1023) / 1024;          // edge slices (~1024 edges each)
    int EPS = (E + FS - 1) / FS;
    int FI_BLK = 8 * FS;                 // 8 shard-blocks per slice
    int CV_BLK = (E + 1023) / 1024;

    hipMemsetAsync(cnt, 0, (size_t)(N + 1) * sizeof(int), stream);
    detect_kernel<<<1, 256, 0, stream>>>(x, ei, flags);
    convert_edges<<<CV_BLK, 256, 0, stream>>>(flags, ei, pe, E, N);
    prep_all<<<NT_BLK + WC_BLK + FI_BLK, 256, 0, stream>>>(flags, x, Wnt, bnt, Wt, Wih, Whh,
                                                           bih, bhh, htA, WCh, WCl, WVh, WVl, B,
                                                           pe, cnt, ss16, novf, ovf,
                                                           E, N, NT_BLK, WC_BLK, EPS);

    u16* hcur = htA;
    u16* hnxt = htB;
    for (int layer = 0; layer < 3; ++layer) {
        bool last = (layer == 2);
        layer_fused<<<(N + NPB - 1) / NPB, 256, 0, stream>>>(flags, hcur, cnt, ss16, novf, ovf,
                                                             WCh + layer * 12288, WCl + layer * 12288,
                                                             WVh, WVl, B,
                                                             last ? nullptr : hnxt,
                                                             last ? d_out : nullptr, N);
        u16* t = hcur; hcur = hnxt; hnxt = t;
    }
}

// Round 5
// 299.149 us; speedup vs baseline: 1.3716x; 1.0476x over previous
//
#include <hip/hip_runtime.h>
#include <hip/hip_bf16.h>
#include <stdint.h>

#define D 64
typedef __hip_bfloat16 bf16;
typedef unsigned short u16;
typedef __attribute__((ext_vector_type(8))) short bf16x8;
typedef __attribute__((ext_vector_type(4))) float f32x4;

__device__ __forceinline__ float bf2f(u16 u) { return __uint_as_float(((uint32_t)u) << 16); }
__device__ __forceinline__ u16 f2bf(float f) { return __bfloat16_as_ushort(__float2bfloat16(f)); }

template <bool F32>
__device__ __forceinline__ float ld(const void* p, int i) {
    if constexpr (F32) return ((const float*)p)[i];
    else return bf2f(((const u16*)p)[i]);
}

// ---- dtype oracle (proven): flags[0]=1 -> fp32 floats; flags[1]=1 -> int32 idx ----
__global__ __launch_bounds__(256) void detect_kernel(const void* x, const int* ei, int* flags) {
    __shared__ float smax[256];
    __shared__ int sor[256];
    int t = threadIdx.x;
    const u16* xs = (const u16*)x;
    float mx = 0.f;
#pragma unroll
    for (int i = 0; i < 16; ++i) {
        float a = fabsf(bf2f(xs[t * 16 + i]));
        if (!(a == a)) a = 1e30f;
        mx = fmaxf(mx, a);
    }
    int any = 0;
#pragma unroll
    for (int i = 0; i < 8; ++i) any |= ei[2 * (t * 8 + i) + 1];
    smax[t] = mx; sor[t] = any;
    __syncthreads();
    for (int s = 128; s > 0; s >>= 1) {
        if (t < s) { smax[t] = fmaxf(smax[t], smax[t + s]); sor[t] |= sor[t + s]; }
        __syncthreads();
    }
    if (t == 0) { flags[0] = (smax[0] > 1000.f) ? 1 : 0; flags[1] = (sor[0] != 0) ? 1 : 0; }
}

// ---- convert_edges: ei (i64/i32) -> packed u32 (src16 | dst16<<16); sentinel 0xFFFFFFFF ----
__global__ __launch_bounds__(256) void convert_edges(const int* __restrict__ flags,
                                                     const int* __restrict__ ei,
                                                     uint32_t* __restrict__ pe, int E, int N) {
    int i0 = blockIdx.x * 1024 + threadIdx.x;
    bool i32 = flags[1] != 0;
#pragma unroll
    for (int u = 0; u < 4; ++u) {
        int i = i0 + u * 256;
        if (i < E) {
            int src, dst;
            if (i32) { src = ei[i];     dst = ei[E + i]; }
            else     { src = ei[2 * i]; dst = ei[2 * (E + i)]; }
            uint32_t v;
            if ((unsigned)src >= (unsigned)N || (unsigned)dst >= (unsigned)N) v = 0xFFFFFFFFu;
            else v = (uint32_t)(u16)src | ((uint32_t)dst << 16);
            pe[i] = v;
        }
    }
}

// ---- prep_all: nt (h0 -> bf16 table) + combined weights (bf16 hi/lo) + XCD-sharded fill ----
//  Fill: 8 blocks per edge-slice; block keeps edges with (dst>>4)&7 == blockIdx&7.
//  b&7 over 8 consecutive blocks is a bijection onto {0..7} -> exact coverage regardless
//  of dispatch mapping; XCD-locality of cnt/ss16 lines is the perf heuristic (G16-safe).
#define N_WCT 36864
#define N_WTH 12288
#define N_B   384
template <bool F32>
__device__ __forceinline__ void nt_body(const void* x, const void* Wnt, const void* bnt,
                                        u16* ht, int N, int blk) {
    int gid = blk * 256 + threadIdx.x;
    if (gid >= N * D) return;
    int n = gid >> 6, c = gid & 63;
    float acc = ld<F32>(bnt, c);
#pragma unroll
    for (int k = 0; k < 6; ++k)
        acc = fmaf(ld<F32>(x, n * 6 + k), ld<F32>(Wnt, c * 6 + k), acc);
    ht[gid] = f2bf(fmaxf(acc, 0.f));
}
template <bool F32>
__device__ __forceinline__ void wc_body(const void* W, const void* Wih, const void* Whh,
                                        const void* bih, const void* bhh,
                                        u16* WCh, u16* WCl, u16* WVh, u16* WVl,
                                        float* B, int blk) {
    int i = blk * 256 + threadIdx.x;
    if (i < N_WCT) {
        int l = i / 12288, rem = i % 12288, k = rem / 192, r = rem % 192;
        float acc = 0.f;
#pragma unroll 8
        for (int j = 0; j < 64; ++j)
            acc = fmaf(ld<F32>(W, l * 4096 + k * 64 + j), ld<F32>(Wih, r * 64 + j), acc);
        u16 hi = f2bf(acc);
        WCh[l * 12288 + r * 64 + k] = hi;
        WCl[l * 12288 + r * 64 + k] = f2bf(acc - bf2f(hi));
    } else if (i < N_WCT + N_WTH) {
        int rem = i - N_WCT;
        int k = rem / 192, r = rem % 192;
        float v = ld<F32>(Whh, r * 64 + k);
        u16 hi = f2bf(v);
        WVh[r * 64 + k] = hi;
        WVl[r * 64 + k] = f2bf(v - bf2f(hi));
    } else if (i < N_WCT + N_WTH + N_B) {
        int rem = i - N_WCT - N_WTH;
        B[rem] = (rem < 192) ? ld<F32>(bih, rem) : ld<F32>(bhh, rem - 192);
    }
}
__global__ __launch_bounds__(256) void prep_all(const int* __restrict__ flags,
                                                const void* x, const void* Wnt, const void* bnt,
                                                const void* W, const void* Wih, const void* Whh,
                                                const void* bih, const void* bhh,
                                                u16* ht, u16* WCh, u16* WCl, u16* WVh, u16* WVl,
                                                float* B,
                                                const uint32_t* __restrict__ pe,
                                                int* __restrict__ cnt,
                                                u16* __restrict__ ss16, int* __restrict__ novf,
                                                int* __restrict__ ovf,
                                                int E, int N, int NT_BLK, int WC_BLK, int EPS) {
    int b = blockIdx.x;
    if (b < NT_BLK) {
        if (flags[0]) nt_body<true>(x, Wnt, bnt, ht, N, b);
        else          nt_body<false>(x, Wnt, bnt, ht, N, b);
    } else if (b < NT_BLK + WC_BLK) {
        if (flags[0]) wc_body<true>(W, Wih, Whh, bih, bhh, WCh, WCl, WVh, WVl, B, b - NT_BLK);
        else          wc_body<false>(W, Wih, Whh, bih, bhh, WCh, WCl, WVh, WVl, B, b - NT_BLK);
    } else {
        int bf = b - NT_BLK - WC_BLK;
        unsigned shard = (unsigned)(b & 7);      // bijection per 8-block group; == XCD id under RR
        int beg = (bf >> 3) * EPS;
        int end = beg + EPS; if (end > E) end = E;
        for (int i = beg + (int)threadIdx.x; i < end; i += 256) {
            uint32_t e = pe[i];
            int dst = (int)(e >> 16);
            if ((((unsigned)dst >> 4) & 7u) != shard) continue;  // one XCD per cnt/ss16 line
            if (dst >= N) continue;                              // sentinel filtered here
            int src = (int)(e & 0xffffu);
            int pos = atomicAdd(&cnt[dst], 1);
            if (pos < 64) ss16[(size_t)dst * 64 + pos] = (u16)src;
            else {
                int o = atomicAdd(novf, 1);
                if (o < E) { ovf[2 * o] = dst; ovf[2 * o + 1] = src; }  // hardened vs OOB
            }
        }
    }
}

// ======= fused layer: 16 nodes/block; packed-dword half-wave gather; gates on MFMA =======
#define NPB 16
#define LSTR 68

// Packed gather: lanes 0-31 (half=0) take even neighbors, lanes 32-63 odd.
// Each lane loads ONE dword (= channels 2*col, 2*col+1) of its neighbor's ht row:
// one VMEM covers 2 rows, one bpermute delivers 2 indices (per-lane src = 2q+half).
// Invalid slots: idx clamped to row 0 BEFORE load, dword zeroed (unpacks to +0.0f).
#define GPACK(P, JB, E0, E1) \
    _Pragma("unroll") for (int q_ = 0; q_ < 8; ++q_) { \
        int j_ = (JB) + 2 * q_ + half; \
        int ix_ = __shfl(iv[P], j_); \
        bool vq_ = j_ < dg[P]; \
        uint32_t d_ = htd[(uint32_t)(vq_ ? ix_ : 0) * 32u + (uint32_t)col]; \
        d_ = vq_ ? d_ : 0u; \
        E0 += __uint_as_float(d_ << 16); \
        E1 += __uint_as_float(d_ & 0xffff0000u); }

__global__ __launch_bounds__(256, 3) void layer_fused(const int* __restrict__ flags,
                                                   const u16* __restrict__ ht,
                                                   const int* __restrict__ cnt,
                                                   const u16* __restrict__ ss16,
                                                   const int* __restrict__ novf,
                                                   const int* __restrict__ ovf,
                                                   const u16* __restrict__ WCh,
                                                   const u16* __restrict__ WCl,
                                                   const u16* __restrict__ WVh,
                                                   const u16* __restrict__ WVl,
                                                   const float* __restrict__ B,
                                                   u16* __restrict__ houtb,
                                                   void* __restrict__ dout,
                                                   int N) {
    __shared__ alignas(16) float LA[NPB * LSTR];
    __shared__ alignas(16) float LH[NPB * LSTR];
    __shared__ alignas(16) u16 Ahi[NPB * 64];
    __shared__ alignas(16) u16 Alo[NPB * 64];
    __shared__ alignas(16) u16 Hb[NPB * 64];
    int t = threadIdx.x;
    int n0 = blockIdx.x * NPB;
    int lane = t & 63;
    int w = t >> 6;
    int w4 = w * 4;
    int half = lane >> 5;
    int col = lane & 31;
    const uint32_t* htd = (const uint32_t*)ht;

    {   // stage own h rows: LH fp32 (epilogue) + Hb bf16 tile (MFMA A, swizzled)
        if (t < 128) {
            int row = t >> 3, c = (t & 7) * 8;
            bool v = (n0 + row) < N;
            uint4 vh = make_uint4(0u, 0u, 0u, 0u);
            if (v) vh = *(const uint4*)(ht + (size_t)(n0 + row) * D + c);
            float4 f0, f1;
            f0.x = bf2f((u16)(vh.x & 0xffff)); f0.y = bf2f((u16)(vh.x >> 16));
            f0.z = bf2f((u16)(vh.y & 0xffff)); f0.w = bf2f((u16)(vh.y >> 16));
            f1.x = bf2f((u16)(vh.z & 0xffff)); f1.y = bf2f((u16)(vh.z >> 16));
            f1.z = bf2f((u16)(vh.w & 0xffff)); f1.w = bf2f((u16)(vh.w >> 16));
            *(float4*)&LH[row * LSTR + c]     = f0;
            *(float4*)&LH[row * LSTR + c + 4] = f1;
            *(uint4*)((char*)Hb + row * 128 + ((c * 2) ^ ((row & 7) << 4))) = vh;
        }
    }

    // ---- gather: lane-parallel index preload; packed half-wave batches ----
    int dg[4]; int iv[4];
#pragma unroll
    for (int p = 0; p < 4; ++p) {
        int n = n0 + w4 + p;
        dg[p] = 0; iv[p] = 0;
        if (n < N) {
            int c = cnt[n]; dg[p] = (c > 64) ? 64 : c;
            iv[p] = (int)ss16[(size_t)n * 64 + lane];
        }
    }
    float e00 = 0.f, e01 = 0.f, e10 = 0.f, e11 = 0.f;
    float e20 = 0.f, e21 = 0.f, e30 = 0.f, e31 = 0.f;
    // stage A: neighbors 0..15 of ALL 4 nodes -> 32 dword loads in flight (64 rows)
    GPACK(0, 0, e00, e01) GPACK(1, 0, e10, e11) GPACK(2, 0, e20, e21) GPACK(3, 0, e30, e31)
    // stage B: neighbors 16..31, wave-uniform skip
    if (dg[0] > 16) GPACK(0, 16, e00, e01)
    if (dg[1] > 16) GPACK(1, 16, e10, e11)
    if (dg[2] > 16) GPACK(2, 16, e20, e21)
    if (dg[3] > 16) GPACK(3, 16, e30, e31)
    // merge halves: after this, both halves hold the full sum for channels (2col, 2col+1)
    e00 += __shfl_xor(e00, 32); e01 += __shfl_xor(e01, 32);
    e10 += __shfl_xor(e10, 32); e11 += __shfl_xor(e11, 32);
    e20 += __shfl_xor(e20, 32); e21 += __shfl_xor(e21, 32);
    e30 += __shfl_xor(e30, 32); e31 += __shfl_xor(e31, 32);
    // scalar tail 32..dg (P ~ 2e-4): post-merge, both halves add identically (consistent copies)
#define GTAIL(P, E0, E1) if (dg[P] > 32) { \
        for (int j = 32; j < dg[P]; ++j) { \
            uint32_t d_ = htd[(uint32_t)__shfl(iv[P], j) * 32u + (uint32_t)col]; \
            E0 += __uint_as_float(d_ << 16); \
            E1 += __uint_as_float(d_ & 0xffff0000u); } }
    GTAIL(0, e00, e01) GTAIL(1, e10, e11) GTAIL(2, e20, e21) GTAIL(3, e30, e31)
    if (half == 0) {
        float2 v0 = {e00, e01}, v1 = {e10, e11}, v2 = {e20, e21}, v3 = {e30, e31};
        *(float2*)&LA[(w4 + 0) * LSTR + 2 * col] = v0;
        *(float2*)&LA[(w4 + 1) * LSTR + 2 * col] = v1;
        *(float2*)&LA[(w4 + 2) * LSTR + 2 * col] = v2;
        *(float2*)&LA[(w4 + 3) * LSTR + 2 * col] = v3;
    }
    __syncthreads();
    {   // exact overflow drain (novf==0 in practice)
        int nv = novf[0];
        if (nv > 0) {
            if (nv > (1 << 20)) nv = (1 << 20);
            for (int o = w; o < nv; o += 4) {
                int dst = ovf[2 * o];
                if (dst >= n0 && dst < n0 + NPB) {
                    int src = ovf[2 * o + 1];
                    atomicAdd(&LA[(dst - n0) * LSTR + lane], bf2f(ht[(size_t)src * D + lane]));
                }
            }
        }
    }
    __syncthreads();
    {   // convert agg fp32 -> Ahi/Alo bf16 tiles (swizzled 8B stores)
        int row = t >> 4, c = (t & 15) * 4;
        float4 v = *(const float4*)&LA[row * LSTR + c];
        u16 h0 = f2bf(v.x), h1 = f2bf(v.y), h2 = f2bf(v.z), h3 = f2bf(v.w);
        uint2 hh, llv;
        hh.x = (uint32_t)h0 | ((uint32_t)h1 << 16);
        hh.y = (uint32_t)h2 | ((uint32_t)h3 << 16);
        llv.x = (uint32_t)f2bf(v.x - bf2f(h0)) | ((uint32_t)f2bf(v.y - bf2f(h1)) << 16);
        llv.y = (uint32_t)f2bf(v.z - bf2f(h2)) | ((uint32_t)f2bf(v.w - bf2f(h3)) << 16);
        int off = row * 128 + ((c * 2) ^ ((row & 7) << 4));
        *(uint2*)((char*)Ahi + off) = hh;
        *(uint2*)((char*)Alo + off) = llv;
    }
    __syncthreads();

    // ---- MFMA gate GEMMs ----
    int r = lane & 15, g = lane >> 4;
    int aoff0 = r * 128 + (((g * 16) + 0) ^ ((r & 7) << 4));
    int aoff1 = r * 128 + (((g * 16) + 64) ^ ((r & 7) << 4));
    bf16x8 aH0 = *(const bf16x8*)((const char*)Ahi + aoff0);
    bf16x8 aH1 = *(const bf16x8*)((const char*)Ahi + aoff1);
    bf16x8 aL0 = *(const bf16x8*)((const char*)Alo + aoff0);
    bf16x8 aL1 = *(const bf16x8*)((const char*)Alo + aoff1);
    bf16x8 hB0 = *(const bf16x8*)((const char*)Hb + aoff0);
    bf16x8 hB1 = *(const bf16x8*)((const char*)Hb + aoff1);

#define WFRAG(P, nt, ks) (*(const bf16x8*)((const char*)(P) + ((nt) * 16 + r) * 128 + (ks) * 64 + g * 16))
#define DO_TILE(nt, ai, ah) { \
    bf16x8 wch0 = WFRAG(WCh, nt, 0), wch1 = WFRAG(WCh, nt, 1); \
    bf16x8 wcl0 = WFRAG(WCl, nt, 0), wcl1 = WFRAG(WCl, nt, 1); \
    bf16x8 wvh0 = WFRAG(WVh, nt, 0), wvh1 = WFRAG(WVh, nt, 1); \
    bf16x8 wvl0 = WFRAG(WVl, nt, 0), wvl1 = WFRAG(WVl, nt, 1); \
    ai = __builtin_amdgcn_mfma_f32_16x16x32_bf16(aH0, wch0, ai, 0, 0, 0); \
    ai = __builtin_amdgcn_mfma_f32_16x16x32_bf16(aH1, wch1, ai, 0, 0, 0); \
    ai = __builtin_amdgcn_mfma_f32_16x16x32_bf16(aL0, wch0, ai, 0, 0, 0); \
    ai = __builtin_amdgcn_mfma_f32_16x16x32_bf16(aL1, wch1, ai, 0, 0, 0); \
    ai = __builtin_amdgcn_mfma_f32_16x16x32_bf16(aH0, wcl0, ai, 0, 0, 0); \
    ai = __builtin_amdgcn_mfma_f32_16x16x32_bf16(aH1, wcl1, ai, 0, 0, 0); \
    ah = __builtin_amdgcn_mfma_f32_16x16x32_bf16(hB0, wvh0, ah, 0, 0, 0); \
    ah = __builtin_amdgcn_mfma_f32_16x16x32_bf16(hB1, wvh1, ah, 0, 0, 0); \
    ah = __builtin_amdgcn_mfma_f32_16x16x32_bf16(hB0, wvl0, ah, 0, 0, 0); \
    ah = __builtin_amdgcn_mfma_f32_16x16x32_bf16(hB1, wvl1, ah, 0, 0, 0); }

    f32x4 air = {0.f, 0.f, 0.f, 0.f}, aiz = air, ain = air;
    f32x4 ahr = air, ahz = air, ahn = air;
    DO_TILE(w, air, ahr);
    DO_TILE(w + 4, aiz, ahz);
    DO_TILE(w + 8, ain, ahn);

    // ---- epilogue: lane holds (4 nodes) x (1 channel); all gates in registers ----
    {
        int ch = w * 16 + r;
        float br = B[ch] + B[192 + ch];
        float bz = B[64 + ch] + B[256 + ch];
        float bi = B[128 + ch];
        float bh = B[320 + ch];
        int nb = g * 4;
#pragma unroll
        for (int j = 0; j < 4; ++j) {
            float gr = air[j] + ahr[j] + br;
            float gz = aiz[j] + ahz[j] + bz;
            float rr = 1.f / (1.f + __expf(-gr));
            float zz = 1.f / (1.f + __expf(-gz));
            float nx = ain[j] + bi + rr * (ahn[j] + bh);
            float th = 1.f - 2.f / (1.f + __expf(2.f * nx));  // tanh, overflow-safe
            float hold = LH[(nb + j) * LSTR + ch];
            LA[(nb + j) * LSTR + ch] = (1.f - zz) * th + zz * hold;
        }
    }
    __syncthreads();
    // ---- coalesced store-out ----
    if (t < 128) {
        int row = t >> 3, c = (t & 7) * 8;
        int n = n0 + row;
        if (n < N) {
            float4 v0 = *(const float4*)&LA[row * LSTR + c];
            float4 v1 = *(const float4*)&LA[row * LSTR + c + 4];
            size_t idx = (size_t)n * D + c;
            if (houtb || !flags[0]) {
                uint4 o;
                o.x = (uint32_t)f2bf(v0.x) | ((uint32_t)f2bf(v0.y) << 16);
                o.y = (uint32_t)f2bf(v0.z) | ((uint32_t)f2bf(v0.w) << 16);
                o.z = (uint32_t)f2bf(v1.x) | ((uint32_t)f2bf(v1.y) << 16);
                o.w = (uint32_t)f2bf(v1.z) | ((uint32_t)f2bf(v1.w) << 16);
                if (houtb) *(uint4*)(houtb + idx) = o;
                else       *(uint4*)((u16*)dout + idx) = o;
            } else {
                *(float4*)((float*)dout + idx)     = v0;
                *(float4*)((float*)dout + idx + 4) = v1;
            }
        }
    }
}

extern "C" void kernel_launch(void* const* d_in, const int* in_sizes, int n_in,
                              void* d_out, int out_size, void* d_ws, size_t ws_size,
                              hipStream_t stream) {
    const void* x   = d_in[0];
    const int*  ei  = (const int*)d_in[1];
    const void* Wnt = d_in[4];
    const void* bnt = d_in[5];
    const void* Wt  = d_in[6];   // [3,64,64]
    const void* Wih = d_in[7];   // [192,64]
    const void* Whh = d_in[8];
    const void* bih = d_in[9];
    const void* bhh = d_in[10];

    int N = in_sizes[0] / 6;
    int E = in_sizes[1] / 2;
    int ND = N * D;

    // Workspace (~29 MB, within proven 38.4 MB):
    // flags(256B) | B | WCh | WCl | WVh | WVl | htA | htB | cnt(N) | novf | ss16 | ovf(2E) | pe(E)
    int* flags = (int*)d_ws;
    float* B   = (float*)((char*)d_ws + 256);
    u16* WCh = (u16*)(B + N_B);          // 3*192*64 bf16
    u16* WCl = WCh + N_WCT;
    u16* WVh = WCl + N_WCT;              // 192*64 bf16
    u16* WVl = WVh + N_WTH;
    u16* htA = WVl + N_WTH;              // 16B-aligned (and 128B-aligned rows)
    u16* htB = htA + ND;
    int* cnt  = (int*)(htB + ND);
    int* novf = cnt + N;
    u16* ss16 = (u16*)(novf + 1);
    int* ovf  = (int*)(ss16 + (size_t)N * 64);
    uint32_t* pe = (uint32_t*)(ovf + 2 * (size_t)E);

    int NT_BLK = (ND + 255) / 256;
    int WC_BLK = (N_WCT + N_WTH + N_B + 255) / 256;
    int FS = (E + 1023) / 1024;          // edge slices (~1024 edges each)
    int EPS = (E + FS - 1) / FS;
    int FI_BLK = 8 * FS;                 // 8 shard-blocks per slice
    int CV_BLK = (E + 1023) / 1024;

    hipMemsetAsync(cnt, 0, (size_t)(N + 1) * sizeof(int), stream);
    detect_kernel<<<1, 256, 0, stream>>>(x, ei, flags);
    convert_edges<<<CV_BLK, 256, 0, stream>>>(flags, ei, pe, E, N);
    prep_all<<<NT_BLK + WC_BLK + FI_BLK, 256, 0, stream>>>(flags, x, Wnt, bnt, Wt, Wih, Whh,
                                                           bih, bhh, htA, WCh, WCl, WVh, WVl, B,
                                                           pe, cnt, ss16, novf, ovf,
                                                           E, N, NT_BLK, WC_BLK, EPS);

    u16* hcur = htA;
    u16* hnxt = htB;
    for (int layer = 0; layer < 3; ++layer) {
        bool last = (layer == 2);
        layer_fused<<<(N + NPB - 1) / NPB, 256, 0, stream>>>(flags, hcur, cnt, ss16, novf, ovf,
                                                             WCh + layer * 12288, WCl + layer * 12288,
                                                             WVh, WVl, B,
                                                             last ? nullptr : hnxt,
                                                             last ? d_out : nullptr, N);
        u16* t = hcur; hcur = hnxt; hnxt = t;
    }
}